// Round 1
// baseline (65.143 us; speedup 1.0000x reference)
//
#include <hip/hip_runtime.h>

// out[b,v,c] = sum_k evecs[b,v,k]^2 * exp(-evals[b,k] * scale[c])
// scale[c] = 10^(-2 + 2c/15), c in [0,16)
// B=8, V=50000, K=128, COUNT=16. All fp32.

constexpr int B_   = 8;
constexpr int V_   = 50000;
constexpr int K_   = 128;
constexpr int CNT  = 16;
constexpr int TPB  = 256;

__global__ __launch_bounds__(TPB) void hks_heat_kernel(
    const float* __restrict__ evals,   // [B, K]
    const float* __restrict__ evecs,   // [B, V, K]
    float* __restrict__ out)           // [B, V, CNT]
{
    // coef[c][k] = exp(-evals[b,k] * scale[c]); 16*128 floats = 8 KB LDS
    __shared__ float4 coef4[CNT * K_ / 4];
    float* coef = (float*)coef4;

    const int b = blockIdx.y;

    // Fill coef table: 2048 entries, 256 threads -> 8 each.
    for (int i = threadIdx.x; i < CNT * K_; i += TPB) {
        const int c = i >> 7;        // i / 128
        const int k = i & (K_ - 1);  // i % 128
        const float s = powf(10.0f, -2.0f + (float)c * (2.0f / 15.0f));
        coef[i] = expf(-evals[b * K_ + k] * s);
    }
    __syncthreads();

    const int v = blockIdx.x * TPB + threadIdx.x;
    if (v >= V_) return;

    const float4* __restrict__ row =
        (const float4*)(evecs + ((long)b * V_ + v) * K_);

    float acc[CNT];
#pragma unroll
    for (int c = 0; c < CNT; ++c) acc[c] = 0.0f;

#pragma unroll 4
    for (int j = 0; j < K_ / 4; ++j) {
        const float4 e = row[j];
        const float x = e.x * e.x;
        const float y = e.y * e.y;
        const float z = e.z * e.z;
        const float w = e.w * e.w;
#pragma unroll
        for (int c = 0; c < CNT; ++c) {
            // Wave-uniform address -> LDS broadcast, conflict-free.
            const float4 q = coef4[c * (K_ / 4) + j];
            acc[c] += x * q.x;
            acc[c] += y * q.y;
            acc[c] += z * q.z;
            acc[c] += w * q.w;
        }
    }

    // 64 B contiguous store per thread as 4x float4.
    float4* o = (float4*)(out + ((long)b * V_ + v) * CNT);
#pragma unroll
    for (int q = 0; q < 4; ++q)
        o[q] = make_float4(acc[4 * q + 0], acc[4 * q + 1],
                           acc[4 * q + 2], acc[4 * q + 3]);
}

extern "C" void kernel_launch(void* const* d_in, const int* in_sizes, int n_in,
                              void* d_out, int out_size, void* d_ws, size_t ws_size,
                              hipStream_t stream) {
    const float* evals = (const float*)d_in[0];  // [8,128]
    const float* evecs = (const float*)d_in[1];  // [8,50000,128]
    float* out = (float*)d_out;                  // [8,50000,16]

    dim3 grid((V_ + TPB - 1) / TPB, B_);
    hks_heat_kernel<<<grid, TPB, 0, stream>>>(evals, evecs, out);
}